// Round 1
// baseline (4172.493 us; speedup 1.0000x reference)
//
#include <hip/hip_runtime.h>

#define NFULL 8192
#define BATCH 4

// ---------------------------------------------------------------- kNN ------
// One thread per query; refs streamed through LDS tiles; top-K kept sorted
// ascending in registers with strict-< insertion (stable ties => matches
// jax.lax.top_k tie-break by lower index). d2 = |q|^2+|r|^2-2q.r (ref formula).
template<int K>
__global__ __launch_bounds__(256) void knn_kernel(
    const float* __restrict__ pos, int Nref, int Mq,
    int* __restrict__ oidx, float* __restrict__ od2) {
  const int TILE = 512;
  __shared__ float sx[TILE], sy[TILE], sz[TILE], srr[TILE];
  int b = blockIdx.y;
  int q = blockIdx.x * blockDim.x + threadIdx.x;
  const float* pb = pos + (size_t)b * NFULL * 3;
  bool active = q < Mq;
  float qx = 0.f, qy = 0.f, qz = 0.f, qq = 0.f;
  if (active) {
    qx = pb[q * 3 + 0]; qy = pb[q * 3 + 1]; qz = pb[q * 3 + 2];
    qq = qx * qx + qy * qy + qz * qz;
  }
  float dist[K]; int ida[K];
#pragma unroll
  for (int i = 0; i < K; ++i) { dist[i] = 3.4e38f; ida[i] = 0; }

  for (int t0 = 0; t0 < Nref; t0 += TILE) {
    int cnt = min(TILE, Nref - t0);
    for (int j = threadIdx.x; j < cnt; j += blockDim.x) {
      float rx = pb[(t0 + j) * 3 + 0];
      float ry = pb[(t0 + j) * 3 + 1];
      float rz = pb[(t0 + j) * 3 + 2];
      sx[j] = rx; sy[j] = ry; sz[j] = rz;
      srr[j] = rx * rx + ry * ry + rz * rz;
    }
    __syncthreads();
    if (active) {
      for (int j = 0; j < cnt; ++j) {
        float d2 = qq + srr[j] - 2.0f * (qx * sx[j] + qy * sy[j] + qz * sz[j]);
        if (d2 < dist[K - 1]) {
          dist[K - 1] = d2; ida[K - 1] = t0 + j;
#pragma unroll
          for (int s = K - 1; s > 0; --s) {
            if (dist[s] < dist[s - 1]) {
              float td = dist[s]; dist[s] = dist[s - 1]; dist[s - 1] = td;
              int ti = ida[s]; ida[s] = ida[s - 1]; ida[s - 1] = ti;
            }
          }
        }
      }
    }
    __syncthreads();
  }
  if (active) {
#pragma unroll
    for (int i = 0; i < K; ++i) {
      oidx[((size_t)b * Mq + q) * K + i] = ida[i];
      od2[((size_t)b * Mq + q) * K + i] = fmaxf(dist[i], 0.0f);
    }
  }
}

// ------------------------------------------------------------- down MLP ----
// One block per (batch, center). blockDim == CHID == COUT; thread t owns
// output channel t with K=16 register accumulators. feat and h1 staged in LDS,
// read via aligned float4 broadcasts.
template<int FEAT, int FEATP, int CIN, int CHID>
__global__ __launch_bounds__(CHID) void down_kernel(
    const float* __restrict__ pos, const float* __restrict__ xin,
    const int* __restrict__ idx, const float* __restrict__ W1,
    const float* __restrict__ b1, const float* __restrict__ W2,
    const float* __restrict__ b2, float* __restrict__ out,
    int n, int nprev) {
  const int K = 16;
  __shared__ int sIdx[K];
  __shared__ float sCtr[3];
  __shared__ float sFeat[K][FEATP];
  __shared__ float sH1[K][CHID];
  int b = blockIdx.y, q = blockIdx.x, t = threadIdx.x;
  const float* pb = pos + (size_t)b * NFULL * 3;
  const float* xb = xin + (size_t)b * nprev * CIN;
  if (t < K) sIdx[t] = idx[((size_t)b * n + q) * K + t];
  if (t < 3) sCtr[t] = pb[q * 3 + t];
  __syncthreads();
  for (int e = t; e < K * FEATP; e += CHID) {
    int k = e / FEATP, c = e % FEATP;
    float v = 0.f;
    if (c < 3) v = pb[sIdx[k] * 3 + c] - sCtr[c];
    else if (c < FEAT) v = xb[(size_t)sIdx[k] * CIN + (c - 3)];
    sFeat[k][c] = v;
  }
  __syncthreads();
  // layer 1: h1 = relu(feat @ W1 + b1)
  float acc[K];
  float bb = b1[t];
#pragma unroll
  for (int k = 0; k < K; ++k) acc[k] = bb;
  for (int c4 = 0; c4 < FEAT / 4; ++c4) {
    int c = c4 * 4;
    float w0 = W1[(c + 0) * CHID + t];
    float w1 = W1[(c + 1) * CHID + t];
    float w2 = W1[(c + 2) * CHID + t];
    float w3 = W1[(c + 3) * CHID + t];
#pragma unroll
    for (int k = 0; k < K; ++k) {
      float4 f = *(const float4*)&sFeat[k][c];
      acc[k] = fmaf(f.x, w0, acc[k]);
      acc[k] = fmaf(f.y, w1, acc[k]);
      acc[k] = fmaf(f.z, w2, acc[k]);
      acc[k] = fmaf(f.w, w3, acc[k]);
    }
  }
  for (int c = (FEAT / 4) * 4; c < FEAT; ++c) {
    float w = W1[c * CHID + t];
#pragma unroll
    for (int k = 0; k < K; ++k) acc[k] = fmaf(sFeat[k][c], w, acc[k]);
  }
#pragma unroll
  for (int k = 0; k < K; ++k) sH1[k][t] = fmaxf(acc[k], 0.f);
  __syncthreads();
  // layer 2: out = max_k (h1 @ W2 + b2)
  float acc2[K];
  float bb2 = b2[t];
#pragma unroll
  for (int k = 0; k < K; ++k) acc2[k] = bb2;
  for (int c4 = 0; c4 < CHID / 4; ++c4) {
    int c = c4 * 4;
    float w0 = W2[(c + 0) * CHID + t];
    float w1 = W2[(c + 1) * CHID + t];
    float w2 = W2[(c + 2) * CHID + t];
    float w3 = W2[(c + 3) * CHID + t];
#pragma unroll
    for (int k = 0; k < K; ++k) {
      float4 h = *(const float4*)&sH1[k][c];
      acc2[k] = fmaf(h.x, w0, acc2[k]);
      acc2[k] = fmaf(h.y, w1, acc2[k]);
      acc2[k] = fmaf(h.z, w2, acc2[k]);
      acc2[k] = fmaf(h.w, w3, acc2[k]);
    }
  }
  float m = acc2[0];
#pragma unroll
  for (int k = 1; k < K; ++k) m = fmaxf(m, acc2[k]);
  out[((size_t)b * n + q) * CHID + t] = m;
}

// --------------------------------------------------------------- up MLP ----
// One block per (batch, query). 3-NN inverse-distance interpolation of coarse
// features, concat with skip features, one matvec + relu.
template<int CIN, int CPRV, int COUT>
__global__ __launch_bounds__(COUT) void up_kernel(
    const float* __restrict__ xc, int ncoarse,
    const int* __restrict__ idx3, const float* __restrict__ d23,
    const float* __restrict__ prv, const float* __restrict__ W,
    const float* __restrict__ bvec, float* __restrict__ out, int m) {
  const int CTOT = CIN + CPRV;  // multiple of 4 for both instantiations
  __shared__ float sCat[CTOT];
  __shared__ float sW[3];
  __shared__ int sI[3];
  int b = blockIdx.y, q = blockIdx.x, t = threadIdx.x;
  if (t == 0) {
    size_t base = ((size_t)b * m + q) * 3;
    float d0 = d23[base + 0], d1 = d23[base + 1], d2v = d23[base + 2];
    float w0 = 1.f / (d0 + 1e-8f), w1 = 1.f / (d1 + 1e-8f), w2 = 1.f / (d2v + 1e-8f);
    float s = w0 + w1 + w2;
    sW[0] = w0 / s; sW[1] = w1 / s; sW[2] = w2 / s;
    sI[0] = (int)idx3[base + 0]; sI[1] = (int)idx3[base + 1]; sI[2] = (int)idx3[base + 2];
  }
  __syncthreads();
  const float* xb = xc + (size_t)b * ncoarse * CIN;
  const float* pvb = prv + ((size_t)b * m + q) * CPRV;
  for (int c = t; c < CIN; c += COUT)
    sCat[c] = sW[0] * xb[(size_t)sI[0] * CIN + c]
            + sW[1] * xb[(size_t)sI[1] * CIN + c]
            + sW[2] * xb[(size_t)sI[2] * CIN + c];
  for (int c = t; c < CPRV; c += COUT) sCat[CIN + c] = pvb[c];
  __syncthreads();
  float acc = bvec[t];
  for (int c4 = 0; c4 < CTOT / 4; ++c4) {
    int c = 4 * c4;
    float4 v = *(const float4*)&sCat[c];
    acc = fmaf(v.x, W[(c + 0) * COUT + t], acc);
    acc = fmaf(v.y, W[(c + 1) * COUT + t], acc);
    acc = fmaf(v.z, W[(c + 2) * COUT + t], acc);
    acc = fmaf(v.w, W[(c + 3) * COUT + t], acc);
  }
  out[((size_t)b * m + q) * COUT + t] = fmaxf(acc, 0.f);
}

// ---------------------------------------------- fused up2 + final MLP ------
// interp(128) ++ [x0(3), pos0(3)] -> relu(@u2W) -> relu(@fW1) -> @fW2 -> out
__global__ __launch_bounds__(128) void up2_final_kernel(
    const float* __restrict__ xc,  // (B, 2048, 128)
    const int* __restrict__ idx3, const float* __restrict__ d23,
    const float* __restrict__ x0, const float* __restrict__ pos0,
    const float* __restrict__ u2W, const float* __restrict__ u2b,
    const float* __restrict__ fW1, const float* __restrict__ fb1,
    const float* __restrict__ fW2, const float* __restrict__ fb2,
    float* __restrict__ out) {
  __shared__ float sA[136];
  __shared__ float sB[128];
  __shared__ float sW[3];
  __shared__ int sI[3];
  int b = blockIdx.y, q = blockIdx.x, t = threadIdx.x;
  if (t == 0) {
    size_t base = ((size_t)b * NFULL + q) * 3;
    float d0 = d23[base + 0], d1 = d23[base + 1], d2v = d23[base + 2];
    float w0 = 1.f / (d0 + 1e-8f), w1 = 1.f / (d1 + 1e-8f), w2 = 1.f / (d2v + 1e-8f);
    float s = w0 + w1 + w2;
    sW[0] = w0 / s; sW[1] = w1 / s; sW[2] = w2 / s;
    sI[0] = (int)idx3[base + 0]; sI[1] = (int)idx3[base + 1]; sI[2] = (int)idx3[base + 2];
  }
  __syncthreads();
  const float* xb = xc + (size_t)b * 2048 * 128;
  sA[t] = sW[0] * xb[(size_t)sI[0] * 128 + t]
        + sW[1] * xb[(size_t)sI[1] * 128 + t]
        + sW[2] * xb[(size_t)sI[2] * 128 + t];
  if (t < 6) {
    const float* src = (t < 3) ? x0 : pos0;
    int c = (t < 3) ? t : t - 3;
    sA[128 + t] = src[((size_t)b * NFULL + q) * 3 + c];
  }
  __syncthreads();
  // layer 1: relu(cat(134) @ u2W + u2b) -> sB
  float acc = u2b[t];
  for (int c4 = 0; c4 < 33; ++c4) {
    int c = 4 * c4;
    float4 v = *(const float4*)&sA[c];
    acc = fmaf(v.x, u2W[(c + 0) * 128 + t], acc);
    acc = fmaf(v.y, u2W[(c + 1) * 128 + t], acc);
    acc = fmaf(v.z, u2W[(c + 2) * 128 + t], acc);
    acc = fmaf(v.w, u2W[(c + 3) * 128 + t], acc);
  }
  acc = fmaf(sA[132], u2W[132 * 128 + t], acc);
  acc = fmaf(sA[133], u2W[133 * 128 + t], acc);
  sB[t] = fmaxf(acc, 0.f);
  __syncthreads();
  // layer 2: relu(sB @ fW1 + fb1) -> sA   (safe: all sA reads done pre-sync)
  float acc2 = fb1[t];
  for (int c4 = 0; c4 < 32; ++c4) {
    int c = 4 * c4;
    float4 v = *(const float4*)&sB[c];
    acc2 = fmaf(v.x, fW1[(c + 0) * 128 + t], acc2);
    acc2 = fmaf(v.y, fW1[(c + 1) * 128 + t], acc2);
    acc2 = fmaf(v.z, fW1[(c + 2) * 128 + t], acc2);
    acc2 = fmaf(v.w, fW1[(c + 3) * 128 + t], acc2);
  }
  sA[t] = fmaxf(acc2, 0.f);
  __syncthreads();
  // layer 3: sA @ fW2 + fb2 -> out
  float acc3 = fb2[t];
  for (int c4 = 0; c4 < 32; ++c4) {
    int c = 4 * c4;
    float4 v = *(const float4*)&sA[c];
    acc3 = fmaf(v.x, fW2[(c + 0) * 128 + t], acc3);
    acc3 = fmaf(v.y, fW2[(c + 1) * 128 + t], acc3);
    acc3 = fmaf(v.z, fW2[(c + 2) * 128 + t], acc3);
    acc3 = fmaf(v.w, fW2[(c + 3) * 128 + t], acc3);
  }
  out[((size_t)b * NFULL + q) * 128 + t] = acc3;
}

__global__ void copy_kernel(const float* __restrict__ src, float* __restrict__ dst, int n) {
  int i = blockIdx.x * blockDim.x + threadIdx.x;
  if (i < n) dst[i] = src[i];
}

// ------------------------------------------------------------------ launch -
extern "C" void kernel_launch(void* const* d_in, const int* in_sizes, int n_in,
                              void* d_out, int out_size, void* d_ws, size_t ws_size,
                              hipStream_t stream) {
  const float* x    = (const float*)d_in[0];
  const float* pos  = (const float*)d_in[1];
  const float* d0W1 = (const float*)d_in[2];
  const float* d0b1 = (const float*)d_in[3];
  const float* d0W2 = (const float*)d_in[4];
  const float* d0b2 = (const float*)d_in[5];
  const float* d1W1 = (const float*)d_in[6];
  const float* d1b1 = (const float*)d_in[7];
  const float* d1W2 = (const float*)d_in[8];
  const float* d1b2 = (const float*)d_in[9];
  const float* d2W1 = (const float*)d_in[10];
  const float* d2b1 = (const float*)d_in[11];
  const float* d2W2 = (const float*)d_in[12];
  const float* d2b2 = (const float*)d_in[13];
  const float* u0W  = (const float*)d_in[14];
  const float* u0b  = (const float*)d_in[15];
  const float* u1W  = (const float*)d_in[16];
  const float* u1b  = (const float*)d_in[17];
  const float* u2W  = (const float*)d_in[18];
  const float* u2b  = (const float*)d_in[19];
  const float* fW1  = (const float*)d_in[20];
  const float* fb1  = (const float*)d_in[21];
  const float* fW2  = (const float*)d_in[22];
  const float* fb2  = (const float*)d_in[23];

  char* ws = (char*)d_ws;
  // workspace layout (bytes), all regions 256-aligned by construction
  float* x1    = (float*)(ws + 0);         // 4*2048*128*4 = 4194304
  float* x2    = (float*)(ws + 4194304);   // 4*512*256*4  = 2097152
  float* x3    = (float*)(ws + 6291456);   // 4*128*512*4  = 1048576
  float* up0o  = (float*)(ws + 7340032);   // 4*512*256*4  = 2097152
  float* up1o  = (float*)(ws + 9437184);   // 4*2048*128*4 = 4194304
  int*   idx0  = (int*)  (ws + 13631488);  // 4*2048*16*4  = 524288
  int*   idx1  = (int*)  (ws + 14155776);  // 4*512*16*4   = 131072
  int*   idx2  = (int*)  (ws + 14286848);  // 4*128*16*4   = 32768
  float* d2s   = (float*)(ws + 14319616);  // scratch d2 for K=16 knns = 524288
  int*   idxu0 = (int*)  (ws + 14843904);  // 4*512*3*4    = 24576
  float* d2u0  = (float*)(ws + 14868480);  // 24576
  int*   idxu1 = (int*)  (ws + 14893056);  // 4*2048*3*4   = 98304
  float* d2u1  = (float*)(ws + 14991360);  // 98304
  int*   idxu2 = (int*)  (ws + 15089664);  // 4*8192*3*4   = 393216
  float* d2u2  = (float*)(ws + 15482880);  // 393216

  float* out = (float*)d_out;              // (4,8192,128) then pos tail

  // ---- down path ----
  knn_kernel<16><<<dim3(8, BATCH), 256, 0, stream>>>(pos, 8192, 2048, idx0, d2s);
  down_kernel<6, 8, 3, 128><<<dim3(2048, BATCH), 128, 0, stream>>>(
      pos, x, idx0, d0W1, d0b1, d0W2, d0b2, x1, 2048, 8192);
  knn_kernel<16><<<dim3(2, BATCH), 256, 0, stream>>>(pos, 2048, 512, idx1, d2s);
  down_kernel<131, 132, 128, 256><<<dim3(512, BATCH), 256, 0, stream>>>(
      pos, x1, idx1, d1W1, d1b1, d1W2, d1b2, x2, 512, 2048);
  knn_kernel<16><<<dim3(1, BATCH), 256, 0, stream>>>(pos, 512, 128, idx2, d2s);
  down_kernel<259, 260, 256, 512><<<dim3(128, BATCH), 512, 0, stream>>>(
      pos, x2, idx2, d2W1, d2b1, d2W2, d2b2, x3, 128, 512);

  // ---- up path ----
  knn_kernel<3><<<dim3(2, BATCH), 256, 0, stream>>>(pos, 128, 512, idxu0, d2u0);
  up_kernel<512, 256, 256><<<dim3(512, BATCH), 256, 0, stream>>>(
      x3, 128, idxu0, d2u0, x2, u0W, u0b, up0o, 512);
  knn_kernel<3><<<dim3(8, BATCH), 256, 0, stream>>>(pos, 512, 2048, idxu1, d2u1);
  up_kernel<256, 128, 128><<<dim3(2048, BATCH), 128, 0, stream>>>(
      up0o, 512, idxu1, d2u1, x1, u1W, u1b, up1o, 2048);
  knn_kernel<3><<<dim3(32, BATCH), 256, 0, stream>>>(pos, 2048, 8192, idxu2, d2u2);
  up2_final_kernel<<<dim3(8192, BATCH), 128, 0, stream>>>(
      up1o, idxu2, d2u2, x, pos, u2W, u2b, fW1, fb1, fW2, fb2, out);

  // ---- second tuple element: pos passthrough ----
  copy_kernel<<<dim3(384), 256, 0, stream>>>(pos, out + (size_t)BATCH * NFULL * 128,
                                             BATCH * NFULL * 3);
}

// Round 2
// 1104.994 us; speedup vs baseline: 3.7760x; 3.7760x over previous
//
#include <hip/hip_runtime.h>

#define NFULL 8192
#define BATCH 4

typedef unsigned long long u64;
typedef unsigned int u32;

// Total-order bias: monotone map fp32 -> u32 (handles negatives correctly).
__device__ __forceinline__ u32 fbias(float f) {
  u32 u = __float_as_uint(f);
  return (u & 0x80000000u) ? ~u : (u | 0x80000000u);
}
__device__ __forceinline__ float funbias(u32 b) {
  u32 u = (b & 0x80000000u) ? (b & 0x7fffffffu) : ~b;
  return __uint_as_float(u);
}

// ---------------------------------------------------------------- kNN ------
// Wave-per-query. Lanes split refs 64 ways; each lane keeps a sorted local
// top-K of u64 keys (biased-d2 << 32 | idx) => lexicographic (d2, idx) order
// exactly matches jax.lax.top_k stable tie-break. Butterfly shfl_xor merge:
// bitonic lower-half trick + 4-stage bitonic cleanup, all static reg indices.
// K is the register list size (power of 2), KOUT entries are written.
template<int K, int KOUT, int QPB>
__global__ __launch_bounds__(64 * QPB) void knn_kernel(
    const float* __restrict__ pos, int Nref, int Mq,
    int* __restrict__ oidx, float* __restrict__ od2) {
  const int TILE = 256;
  __shared__ float4 sRef[TILE];
  int b = blockIdx.y;
  int w = threadIdx.x >> 6, lane = threadIdx.x & 63;
  int q = blockIdx.x * QPB + w;  // all Mq are multiples of QPB
  const float* pb = pos + (size_t)b * NFULL * 3;
  float qx = pb[q * 3 + 0], qy = pb[q * 3 + 1], qz = pb[q * 3 + 2];
  float qq = qx * qx + qy * qy + qz * qz;

  u64 key[K];
#pragma unroll
  for (int i = 0; i < K; ++i) key[i] = ~0ull;

  for (int t0 = 0; t0 < Nref; t0 += TILE) {
    int cnt = min(TILE, Nref - t0);
    __syncthreads();
    for (int j = threadIdx.x; j < cnt; j += 64 * QPB) {
      float rx = pb[(t0 + j) * 3 + 0];
      float ry = pb[(t0 + j) * 3 + 1];
      float rz = pb[(t0 + j) * 3 + 2];
      sRef[j] = make_float4(rx, ry, rz, rx * rx + ry * ry + rz * rz);
    }
    __syncthreads();
#pragma unroll
    for (int c = 0; c < TILE / 64; ++c) {
      int j = lane + 64 * c;
      if (j < cnt) {
        float4 r = sRef[j];
        float d2 = qq + r.w - 2.0f * (qx * r.x + qy * r.y + qz * r.z);
        u64 ck = ((u64)fbias(d2) << 32) | (u32)(t0 + j);
        if (ck < key[K - 1]) {
          key[K - 1] = ck;
#pragma unroll
          for (int s = K - 1; s > 0; --s) {
            if (key[s] < key[s - 1]) {
              u64 t = key[s]; key[s] = key[s - 1]; key[s - 1] = t;
            }
          }
        }
      }
    }
  }

  // butterfly merge across 64 lanes; everyone converges to global top-K
#pragma unroll
  for (int s = 1; s < 64; s <<= 1) {
    u64 other[K];
#pragma unroll
    for (int i = 0; i < K; ++i)
      other[i] = __shfl_xor((unsigned long long)key[i], s, 64);
    // lower half of bitonic(A ++ rev(B)): the K smallest, as a bitonic seq
#pragma unroll
    for (int i = 0; i < K; ++i) {
      u64 o = other[K - 1 - i];
      key[i] = (key[i] < o) ? key[i] : o;
    }
    // bitonic cleanup: sort ascending
#pragma unroll
    for (int d = K / 2; d >= 1; d >>= 1) {
#pragma unroll
      for (int i = 0; i < K; ++i) {
        if ((i & d) == 0) {
          if (key[i + d] < key[i]) {
            u64 t = key[i]; key[i] = key[i + d]; key[i + d] = t;
          }
        }
      }
    }
  }

  if (lane == 0) {
    size_t base = ((size_t)b * Mq + q) * KOUT;
#pragma unroll
    for (int i = 0; i < KOUT; ++i) {
      oidx[base + i] = (int)(u32)key[i];
      od2[base + i] = fmaxf(funbias((u32)(key[i] >> 32)), 0.0f);
    }
  }
}

// ------------------------------------------------------------- down MLP ----
// One block per (batch, center). blockDim == CHID == COUT; thread t owns
// output channel t with K=16 register accumulators. feat and h1 staged in LDS,
// read via aligned float4 broadcasts.
template<int FEAT, int FEATP, int CIN, int CHID>
__global__ __launch_bounds__(CHID) void down_kernel(
    const float* __restrict__ pos, const float* __restrict__ xin,
    const int* __restrict__ idx, const float* __restrict__ W1,
    const float* __restrict__ b1, const float* __restrict__ W2,
    const float* __restrict__ b2, float* __restrict__ out,
    int n, int nprev) {
  const int K = 16;
  __shared__ int sIdx[K];
  __shared__ float sCtr[3];
  __shared__ float sFeat[K][FEATP];
  __shared__ float sH1[K][CHID];
  int b = blockIdx.y, q = blockIdx.x, t = threadIdx.x;
  const float* pb = pos + (size_t)b * NFULL * 3;
  const float* xb = xin + (size_t)b * nprev * CIN;
  if (t < K) sIdx[t] = idx[((size_t)b * n + q) * K + t];
  if (t < 3) sCtr[t] = pb[q * 3 + t];
  __syncthreads();
  for (int e = t; e < K * FEATP; e += CHID) {
    int k = e / FEATP, c = e % FEATP;
    float v = 0.f;
    if (c < 3) v = pb[sIdx[k] * 3 + c] - sCtr[c];
    else if (c < FEAT) v = xb[(size_t)sIdx[k] * CIN + (c - 3)];
    sFeat[k][c] = v;
  }
  __syncthreads();
  // layer 1: h1 = relu(feat @ W1 + b1)
  float acc[K];
  float bb = b1[t];
#pragma unroll
  for (int k = 0; k < K; ++k) acc[k] = bb;
  for (int c4 = 0; c4 < FEAT / 4; ++c4) {
    int c = c4 * 4;
    float w0 = W1[(c + 0) * CHID + t];
    float w1 = W1[(c + 1) * CHID + t];
    float w2 = W1[(c + 2) * CHID + t];
    float w3 = W1[(c + 3) * CHID + t];
#pragma unroll
    for (int k = 0; k < K; ++k) {
      float4 f = *(const float4*)&sFeat[k][c];
      acc[k] = fmaf(f.x, w0, acc[k]);
      acc[k] = fmaf(f.y, w1, acc[k]);
      acc[k] = fmaf(f.z, w2, acc[k]);
      acc[k] = fmaf(f.w, w3, acc[k]);
    }
  }
  for (int c = (FEAT / 4) * 4; c < FEAT; ++c) {
    float w = W1[c * CHID + t];
#pragma unroll
    for (int k = 0; k < K; ++k) acc[k] = fmaf(sFeat[k][c], w, acc[k]);
  }
#pragma unroll
  for (int k = 0; k < K; ++k) sH1[k][t] = fmaxf(acc[k], 0.f);
  __syncthreads();
  // layer 2: out = max_k (h1 @ W2 + b2)
  float acc2[K];
  float bb2 = b2[t];
#pragma unroll
  for (int k = 0; k < K; ++k) acc2[k] = bb2;
  for (int c4 = 0; c4 < CHID / 4; ++c4) {
    int c = c4 * 4;
    float w0 = W2[(c + 0) * CHID + t];
    float w1 = W2[(c + 1) * CHID + t];
    float w2 = W2[(c + 2) * CHID + t];
    float w3 = W2[(c + 3) * CHID + t];
#pragma unroll
    for (int k = 0; k < K; ++k) {
      float4 h = *(const float4*)&sH1[k][c];
      acc2[k] = fmaf(h.x, w0, acc2[k]);
      acc2[k] = fmaf(h.y, w1, acc2[k]);
      acc2[k] = fmaf(h.z, w2, acc2[k]);
      acc2[k] = fmaf(h.w, w3, acc2[k]);
    }
  }
  float m = acc2[0];
#pragma unroll
  for (int k = 1; k < K; ++k) m = fmaxf(m, acc2[k]);
  out[((size_t)b * n + q) * CHID + t] = m;
}

// --------------------------------------------------------------- up MLP ----
template<int CIN, int CPRV, int COUT>
__global__ __launch_bounds__(COUT) void up_kernel(
    const float* __restrict__ xc, int ncoarse,
    const int* __restrict__ idx3, const float* __restrict__ d23,
    const float* __restrict__ prv, const float* __restrict__ W,
    const float* __restrict__ bvec, float* __restrict__ out, int m) {
  const int CTOT = CIN + CPRV;
  __shared__ float sCat[CTOT];
  __shared__ float sW[3];
  __shared__ int sI[3];
  int b = blockIdx.y, q = blockIdx.x, t = threadIdx.x;
  if (t == 0) {
    size_t base = ((size_t)b * m + q) * 3;
    float d0 = d23[base + 0], d1 = d23[base + 1], d2v = d23[base + 2];
    float w0 = 1.f / (d0 + 1e-8f), w1 = 1.f / (d1 + 1e-8f), w2 = 1.f / (d2v + 1e-8f);
    float s = w0 + w1 + w2;
    sW[0] = w0 / s; sW[1] = w1 / s; sW[2] = w2 / s;
    sI[0] = (int)idx3[base + 0]; sI[1] = (int)idx3[base + 1]; sI[2] = (int)idx3[base + 2];
  }
  __syncthreads();
  const float* xb = xc + (size_t)b * ncoarse * CIN;
  const float* pvb = prv + ((size_t)b * m + q) * CPRV;
  for (int c = t; c < CIN; c += COUT)
    sCat[c] = sW[0] * xb[(size_t)sI[0] * CIN + c]
            + sW[1] * xb[(size_t)sI[1] * CIN + c]
            + sW[2] * xb[(size_t)sI[2] * CIN + c];
  for (int c = t; c < CPRV; c += COUT) sCat[CIN + c] = pvb[c];
  __syncthreads();
  float acc = bvec[t];
  for (int c4 = 0; c4 < CTOT / 4; ++c4) {
    int c = 4 * c4;
    float4 v = *(const float4*)&sCat[c];
    acc = fmaf(v.x, W[(c + 0) * COUT + t], acc);
    acc = fmaf(v.y, W[(c + 1) * COUT + t], acc);
    acc = fmaf(v.z, W[(c + 2) * COUT + t], acc);
    acc = fmaf(v.w, W[(c + 3) * COUT + t], acc);
  }
  out[((size_t)b * m + q) * COUT + t] = fmaxf(acc, 0.f);
}

// ---------------------------------------------- fused up2 + final MLP ------
__global__ __launch_bounds__(128) void up2_final_kernel(
    const float* __restrict__ xc,
    const int* __restrict__ idx3, const float* __restrict__ d23,
    const float* __restrict__ x0, const float* __restrict__ pos0,
    const float* __restrict__ u2W, const float* __restrict__ u2b,
    const float* __restrict__ fW1, const float* __restrict__ fb1,
    const float* __restrict__ fW2, const float* __restrict__ fb2,
    float* __restrict__ out) {
  __shared__ float sA[136];
  __shared__ float sB[128];
  __shared__ float sW[3];
  __shared__ int sI[3];
  int b = blockIdx.y, q = blockIdx.x, t = threadIdx.x;
  if (t == 0) {
    size_t base = ((size_t)b * NFULL + q) * 3;
    float d0 = d23[base + 0], d1 = d23[base + 1], d2v = d23[base + 2];
    float w0 = 1.f / (d0 + 1e-8f), w1 = 1.f / (d1 + 1e-8f), w2 = 1.f / (d2v + 1e-8f);
    float s = w0 + w1 + w2;
    sW[0] = w0 / s; sW[1] = w1 / s; sW[2] = w2 / s;
    sI[0] = (int)idx3[base + 0]; sI[1] = (int)idx3[base + 1]; sI[2] = (int)idx3[base + 2];
  }
  __syncthreads();
  const float* xb = xc + (size_t)b * 2048 * 128;
  sA[t] = sW[0] * xb[(size_t)sI[0] * 128 + t]
        + sW[1] * xb[(size_t)sI[1] * 128 + t]
        + sW[2] * xb[(size_t)sI[2] * 128 + t];
  if (t < 6) {
    const float* src = (t < 3) ? x0 : pos0;
    int c = (t < 3) ? t : t - 3;
    sA[128 + t] = src[((size_t)b * NFULL + q) * 3 + c];
  }
  __syncthreads();
  float acc = u2b[t];
  for (int c4 = 0; c4 < 33; ++c4) {
    int c = 4 * c4;
    float4 v = *(const float4*)&sA[c];
    acc = fmaf(v.x, u2W[(c + 0) * 128 + t], acc);
    acc = fmaf(v.y, u2W[(c + 1) * 128 + t], acc);
    acc = fmaf(v.z, u2W[(c + 2) * 128 + t], acc);
    acc = fmaf(v.w, u2W[(c + 3) * 128 + t], acc);
  }
  acc = fmaf(sA[132], u2W[132 * 128 + t], acc);
  acc = fmaf(sA[133], u2W[133 * 128 + t], acc);
  sB[t] = fmaxf(acc, 0.f);
  __syncthreads();
  float acc2 = fb1[t];
  for (int c4 = 0; c4 < 32; ++c4) {
    int c = 4 * c4;
    float4 v = *(const float4*)&sB[c];
    acc2 = fmaf(v.x, fW1[(c + 0) * 128 + t], acc2);
    acc2 = fmaf(v.y, fW1[(c + 1) * 128 + t], acc2);
    acc2 = fmaf(v.z, fW1[(c + 2) * 128 + t], acc2);
    acc2 = fmaf(v.w, fW1[(c + 3) * 128 + t], acc2);
  }
  sA[t] = fmaxf(acc2, 0.f);
  __syncthreads();
  float acc3 = fb2[t];
  for (int c4 = 0; c4 < 32; ++c4) {
    int c = 4 * c4;
    float4 v = *(const float4*)&sA[c];
    acc3 = fmaf(v.x, fW2[(c + 0) * 128 + t], acc3);
    acc3 = fmaf(v.y, fW2[(c + 1) * 128 + t], acc3);
    acc3 = fmaf(v.z, fW2[(c + 2) * 128 + t], acc3);
    acc3 = fmaf(v.w, fW2[(c + 3) * 128 + t], acc3);
  }
  out[((size_t)b * NFULL + q) * 128 + t] = acc3;
}

__global__ void copy_kernel(const float* __restrict__ src, float* __restrict__ dst, int n) {
  int i = blockIdx.x * blockDim.x + threadIdx.x;
  if (i < n) dst[i] = src[i];
}

// ------------------------------------------------------------------ launch -
extern "C" void kernel_launch(void* const* d_in, const int* in_sizes, int n_in,
                              void* d_out, int out_size, void* d_ws, size_t ws_size,
                              hipStream_t stream) {
  const float* x    = (const float*)d_in[0];
  const float* pos  = (const float*)d_in[1];
  const float* d0W1 = (const float*)d_in[2];
  const float* d0b1 = (const float*)d_in[3];
  const float* d0W2 = (const float*)d_in[4];
  const float* d0b2 = (const float*)d_in[5];
  const float* d1W1 = (const float*)d_in[6];
  const float* d1b1 = (const float*)d_in[7];
  const float* d1W2 = (const float*)d_in[8];
  const float* d1b2 = (const float*)d_in[9];
  const float* d2W1 = (const float*)d_in[10];
  const float* d2b1 = (const float*)d_in[11];
  const float* d2W2 = (const float*)d_in[12];
  const float* d2b2 = (const float*)d_in[13];
  const float* u0W  = (const float*)d_in[14];
  const float* u0b  = (const float*)d_in[15];
  const float* u1W  = (const float*)d_in[16];
  const float* u1b  = (const float*)d_in[17];
  const float* u2W  = (const float*)d_in[18];
  const float* u2b  = (const float*)d_in[19];
  const float* fW1  = (const float*)d_in[20];
  const float* fb1  = (const float*)d_in[21];
  const float* fW2  = (const float*)d_in[22];
  const float* fb2  = (const float*)d_in[23];

  char* ws = (char*)d_ws;
  float* x1    = (float*)(ws + 0);
  float* x2    = (float*)(ws + 4194304);
  float* x3    = (float*)(ws + 6291456);
  float* up0o  = (float*)(ws + 7340032);
  float* up1o  = (float*)(ws + 9437184);
  int*   idx0  = (int*)  (ws + 13631488);
  int*   idx1  = (int*)  (ws + 14155776);
  int*   idx2  = (int*)  (ws + 14286848);
  float* d2s   = (float*)(ws + 14319616);
  int*   idxu0 = (int*)  (ws + 14843904);
  float* d2u0  = (float*)(ws + 14868480);
  int*   idxu1 = (int*)  (ws + 14893056);
  float* d2u1  = (float*)(ws + 14991360);
  int*   idxu2 = (int*)  (ws + 15089664);
  float* d2u2  = (float*)(ws + 15482880);

  float* out = (float*)d_out;

  // ---- down path ----
  knn_kernel<16, 16, 4><<<dim3(512, BATCH), 256, 0, stream>>>(pos, 8192, 2048, idx0, d2s);
  down_kernel<6, 8, 3, 128><<<dim3(2048, BATCH), 128, 0, stream>>>(
      pos, x, idx0, d0W1, d0b1, d0W2, d0b2, x1, 2048, 8192);
  knn_kernel<16, 16, 4><<<dim3(128, BATCH), 256, 0, stream>>>(pos, 2048, 512, idx1, d2s);
  down_kernel<131, 132, 128, 256><<<dim3(512, BATCH), 256, 0, stream>>>(
      pos, x1, idx1, d1W1, d1b1, d1W2, d1b2, x2, 512, 2048);
  knn_kernel<16, 16, 4><<<dim3(32, BATCH), 256, 0, stream>>>(pos, 512, 128, idx2, d2s);
  down_kernel<259, 260, 256, 512><<<dim3(128, BATCH), 512, 0, stream>>>(
      pos, x2, idx2, d2W1, d2b1, d2W2, d2b2, x3, 128, 512);

  // ---- up path ----
  knn_kernel<4, 3, 4><<<dim3(128, BATCH), 256, 0, stream>>>(pos, 128, 512, idxu0, d2u0);
  up_kernel<512, 256, 256><<<dim3(512, BATCH), 256, 0, stream>>>(
      x3, 128, idxu0, d2u0, x2, u0W, u0b, up0o, 512);
  knn_kernel<4, 3, 4><<<dim3(512, BATCH), 256, 0, stream>>>(pos, 512, 2048, idxu1, d2u1);
  up_kernel<256, 128, 128><<<dim3(2048, BATCH), 128, 0, stream>>>(
      up0o, 512, idxu1, d2u1, x1, u1W, u1b, up1o, 2048);
  knn_kernel<4, 3, 4><<<dim3(2048, BATCH), 256, 0, stream>>>(pos, 2048, 8192, idxu2, d2u2);
  up2_final_kernel<<<dim3(8192, BATCH), 128, 0, stream>>>(
      up1o, idxu2, d2u2, x, pos, u2W, u2b, fW1, fb1, fW2, fb2, out);

  // ---- second tuple element: pos passthrough ----
  copy_kernel<<<dim3(384), 256, 0, stream>>>(pos, out + (size_t)BATCH * NFULL * 128,
                                             BATCH * NFULL * 3);
}